// Round 4
// baseline (736.785 us; speedup 1.0000x reference)
//
#include <hip/hip_runtime.h>

// BATCH = 1048576, row = 146 f32 = 584 B = 73 float2 (64 emb f2 + 9 genre f2).
//
// Wave-per-row design (4 rows per wave):
//  - global wave id -> 4 consecutive output rows
//  - item indices via ONE scalar load (s_load_dwordx4): idx addr is
//    wave-uniform (readfirstlane-forced), so table bases live in SGPRs
//  - emb row = exactly 64 float2 -> one perfectly-coalesced 8B/lane load
//    per row (512 B contiguous), no per-element division at all
//  - genre tails of all 4 rows packed into one load (lanes 0..35)
//  - stores: 4x contiguous 512 B NT stores + 1 packed tail NT store
// ~11 vmem instructions per 2336 B of output (was ~45 in the
// thread-per-float4 version that ran ~308 us).

#define BATCH     1048576u
#define ROW_F2    73u
#define EMB_F2    64u
#define GENRE_F2  9u
#define ROWS_PW   4u                         // rows per wave

typedef float f32x2 __attribute__((ext_vector_type(2)));

__global__ __launch_bounds__(256) void item_emb_gather_concat(
    const int*   __restrict__ idx,      // [BATCH] int32
    const f32x2* __restrict__ emb,      // [NUM_ITEMS][64] float2
    const f32x2* __restrict__ genre,    // [NUM_ITEMS][9]  float2
    f32x2*       __restrict__ out)      // [BATCH][73] float2
{
    const unsigned lane = threadIdx.x & 63u;

    // global wave index, forced wave-uniform into SGPR
    unsigned wid_v = (blockIdx.x * 256u + threadIdx.x) >> 6;
    const unsigned wid = (unsigned)__builtin_amdgcn_readfirstlane((int)wid_v);
    const unsigned r0  = wid * ROWS_PW;          // first of 4 consecutive rows

    // one scalar 16B load of the 4 item indices (r0 % 4 == 0 -> aligned)
    const int4 it4 = *reinterpret_cast<const int4*>(idx + r0);
    const unsigned i0 = (unsigned)it4.x;
    const unsigned i1 = (unsigned)it4.y;
    const unsigned i2 = (unsigned)it4.z;
    const unsigned i3 = (unsigned)it4.w;

    // ---- embedding rows: one coalesced 8B/lane load each (SGPR base) ----
    f32x2 e0 = emb[(size_t)i0 * EMB_F2 + lane];
    f32x2 e1 = emb[(size_t)i1 * EMB_F2 + lane];
    f32x2 e2 = emb[(size_t)i2 * EMB_F2 + lane];
    f32x2 e3 = emb[(size_t)i3 * EMB_F2 + lane];

    // ---- genre tails: lanes 0..35 cover 4 rows x 9 float2 ----
    unsigned ri = lane / 9u;                     // sub-row 0..7 (only <4 used)
    unsigned c  = lane - ri * 9u;                // 0..8
    // branchless item select; lanes >=36 fold to i3 (load stays in-bounds,
    // result discarded by the predicated store)
    unsigned item = ri < 2u ? (ri == 0u ? i0 : i1)
                            : (ri == 2u ? i2 : i3);
    f32x2 g = genre[(size_t)item * GENRE_F2 + c];

    // ---- stores (write-once stream: non-temporal) ----
    size_t ob = (size_t)r0 * ROW_F2;
    __builtin_nontemporal_store(e0, &out[ob + 0u * ROW_F2 + lane]);
    __builtin_nontemporal_store(e1, &out[ob + 1u * ROW_F2 + lane]);
    __builtin_nontemporal_store(e2, &out[ob + 2u * ROW_F2 + lane]);
    __builtin_nontemporal_store(e3, &out[ob + 3u * ROW_F2 + lane]);
    if (lane < 36u)
        __builtin_nontemporal_store(g, &out[ob + (size_t)ri * ROW_F2 + EMB_F2 + c]);
}

extern "C" void kernel_launch(void* const* d_in, const int* in_sizes, int n_in,
                              void* d_out, int out_size, void* d_ws, size_t ws_size,
                              hipStream_t stream) {
    const int*   idx   = (const int*)d_in[0];
    const f32x2* emb   = (const f32x2*)d_in[1];
    const f32x2* genre = (const f32x2*)d_in[2];
    f32x2*       out   = (f32x2*)d_out;

    // 4 waves/block * 4 rows/wave = 16 rows per block of 256 threads
    const unsigned block = 256;
    const unsigned grid  = BATCH / 16u;          // 65,536 blocks, exact
    item_emb_gather_concat<<<grid, block, 0, stream>>>(idx, emb, genre, out);
}